// Round 14
// baseline (16618.262 us; speedup 1.0000x reference)
//
#include <hip/hip_runtime.h>

// TimeframeEncoder R14: SINGLE-BLOCK FULL-WEIGHT-RESIDENT recurrence.
// R7-R13 proved the cross-CU pipeline channel is pinned at ~3.1ms regardless
// of fence/cache/issue strategy -> eliminate cross-block traffic entirely.
// 16 blocks x 1024 thr (16 waves, 4/SIMD). Each block owns 16 batch rows and
// runs the whole 512-step recurrence. ALL 1248 weight tiles live in the
// block's 2MB unified register file: per wave 78 tiles = 312 regs, split
// 30 tiles "+v" (layer0, 120 VGPR) + 48 tiles "+a" (layer1, 192 AGPR) --
// the explicit AGPR pin is what R2/R3 lacked (312 "+v" pins can't fit the
// 256-VGPR class -> compiler spilled; unified V+A space fits easily).
// LDS: A-fragment buffers only (52KB). No rings, no counters, no fences.

#define SEQL 512
#define IDIM 64

typedef __bf16 bf16x8 __attribute__((ext_vector_type(8)));
typedef float f32x4 __attribute__((ext_vector_type(4)));

__device__ __forceinline__ unsigned short f2bf(float f) {
  unsigned int u = __builtin_bit_cast(unsigned int, f);
  u += 0x7fffu + ((u >> 16) & 1u);   // RNE
  return (unsigned short)(u >> 16);
}
__device__ __forceinline__ float sigm(float x) { return 1.0f / (1.0f + __expf(-x)); }
__device__ __forceinline__ float tanh_(float x) { return 1.0f - 2.0f / (__expf(2.0f * x) + 1.0f); }
__device__ __forceinline__ float sanit(float v) {
  if (!(v == v)) return 0.f;
  if (isinf(v)) return v > 0.f ? 10.f : -10.f;
  return v;
}

// Weight prep (layout verified R1-R13): bf16 B-fragments, tile = 512 ushort,
// lane L holds B[k=(L>>4)*8+j][n=L&15], j<8. Wz0p tiles [0,320) (nt<32,kt<10);
// Wc0p base 320 (nt<16,kt<10); Wz1p base 480 (nt<32,kt<16); Wc1p base 992.
__global__ __launch_bounds__(256) void prep_weights(
    const float* __restrict__ Wz0, const float* __restrict__ Wc0,
    const float* __restrict__ Wz1, const float* __restrict__ Wc1,
    unsigned short* __restrict__ ws) {
  int idx = blockIdx.x * 256 + threadIdx.x;  // 638976 threads
  const float* W;
  int stride, KT, base;
  if (idx < 163840)      { W = Wz0; stride = 768; KT = 10; base = 0; }
  else if (idx < 245760) { W = Wc0; stride = 256; KT = 10; base = 163840; idx -= 163840; }
  else if (idx < 507904) { W = Wz1; stride = 768; KT = 16; base = 245760; idx -= 245760; }
  else                   { W = Wc1; stride = 256; KT = 16; base = 507904; idx -= 507904; }
  int tile = idx >> 9;
  int t = idx & 511;
  int nt = tile / KT;
  int kt = tile - nt * KT;
  int n15 = t & 15;
  int klocal = t >> 4;
  int k = (kt << 5) + klocal;
  int n = (nt << 4) + n15;
  int lane = ((klocal >> 3) << 4) | n15;
  int j = klocal & 7;
  ws[base + (tile << 9) + (lane << 3) + j] = f2bf(W[k * stride + n]);
}

#define MFMA(a, b, c) __builtin_amdgcn_mfma_f32_16x16x32_bf16((a), (b), (c), 0, 0, 0)

__global__ __launch_bounds__(1024, 4) void gru_main(
    const float* __restrict__ x,
    const float* __restrict__ bz0, const float* __restrict__ bc0,
    const float* __restrict__ bz1, const float* __restrict__ bc1,
    const float* __restrict__ gamma, const float* __restrict__ beta,
    const unsigned short* __restrict__ wsw,
    float* __restrict__ out) {
  __shared__ __align__(16) unsigned short lds[26624];  // 52 KB
  unsigned short* A0   = lds;           // combined0 h0-part, 8 kt
  unsigned short* A0r  = lds + 4096;    // reset0 rh0-part, 8 kt
  unsigned short* A1   = lds + 8192;    // combined1 [h1|h0], 16 kt
  unsigned short* A1r  = lds + 16384;   // reset1 [rh1|h0], 16 kt
  unsigned short* xbuf = lds + 24576;   // x frags, 2 bufs x 2 kt

  const int tid  = threadIdx.x;
  const int wave = tid >> 6;   // 0..15
  const int lane = tid & 63;
  const int l15  = lane & 15;
  const int quad = lane >> 4;
  const int row0 = blockIdx.x << 4;

  for (int i = tid; i < 4096; i += 1024) { A0[i] = 0; A1[i] = 0; }

  const int colz = (wave << 4) | l15;
  const int dlo = ((colz >> 5) << 9) + ((((colz >> 3) & 3) << 4) + (quad << 2)) * 8 + (colz & 7);
  const int dhi = dlo + 4096;  // same element at k += 256 (8 kt further)

  const float bz0z = bz0[colz], bz0r = bz0[256 + colz];
  const float bc0c = bc0[colz];
  const float bz1z = bz1[colz], bz1r = bz1[256 + colz];
  const float bc1c = bc1[colz];

  const bf16x8* __restrict__ wsv = (const bf16x8*)wsw;

  // ---- Stationary B tiles: 78/wave = 312 regs, split across reg classes ----
  bf16x8 pz[10], pr[10], pc[10];   // layer0: 30 tiles = 120 VGPR
  bf16x8 qz[16], qr[16], qc[16];   // layer1: 48 tiles = 192 AGPR
#pragma unroll
  for (int kt = 0; kt < 10; ++kt) {
    pz[kt] = wsv[(wave * 10 + kt) * 64 + lane];
    pr[kt] = wsv[((16 + wave) * 10 + kt) * 64 + lane];
    pc[kt] = wsv[(320 + wave * 10 + kt) * 64 + lane];
  }
#pragma unroll
  for (int kt = 0; kt < 16; ++kt) {
    qz[kt] = wsv[(480 + wave * 16 + kt) * 64 + lane];
    qr[kt] = wsv[(480 + (16 + wave) * 16 + kt) * 64 + lane];
    qc[kt] = wsv[(992 + wave * 16 + kt) * 64 + lane];
  }
#pragma unroll
  for (int kt = 0; kt < 10; ++kt)
    asm volatile("" : "+v"(pz[kt]), "+v"(pr[kt]), "+v"(pc[kt]));
#pragma unroll
  for (int kt = 0; kt < 16; ++kt)
    asm volatile("" : "+a"(qz[kt]), "+a"(qr[kt]), "+a"(qc[kt]));

  // x staging: thread (row=wave, chan=lane) loads x[row0+wave][t][lane]
  const float* xp = x + (size_t)(row0 + wave) * (SEQL * IDIM) + lane;
  const int xdst = ((lane >> 5) << 9) + ((((lane >> 3) & 3) << 4) + wave) * 8 + (lane & 7);
  xbuf[xdst] = f2bf(sanit(xp[0]));   // x[0] -> buffer 0

  f32x4 h0 = {0.f, 0.f, 0.f, 0.f};
  f32x4 h1 = {0.f, 0.f, 0.f, 0.f};

  __syncthreads();

  for (int t = 0; t < SEQL; ++t) {
    const unsigned short* xb = xbuf + ((t & 1) << 10);
    const bool havex = (t < SEQL - 1);
    float xn;
    if (havex) xn = xp[(t + 1) * IDIM];   // prefetch; stored in P5

    // ---- P2: gates0 = [h0|x] @ Wz0[:,:512] + bz0 ----
    f32x4 az = {bz0z, bz0z, bz0z, bz0z};
    f32x4 ar = {bz0r, bz0r, bz0r, bz0r};
#pragma unroll
    for (int kt = 0; kt < 8; ++kt) {
      bf16x8 a = *(const bf16x8*)(A0 + (kt << 9) + (lane << 3));
      az = MFMA(a, pz[kt], az);
      ar = MFMA(a, pr[kt], ar);
    }
#pragma unroll
    for (int kt = 8; kt < 10; ++kt) {
      bf16x8 a = *(const bf16x8*)(xb + ((kt - 8) << 9) + (lane << 3));
      az = MFMA(a, pz[kt], az);
      ar = MFMA(a, pr[kt], ar);
    }
    float z0[4];
#pragma unroll
    for (int i = 0; i < 4; ++i) {
      z0[i] = sigm(az[i]);
      A0r[dlo + i * 8] = f2bf(sigm(ar[i]) * h0[i]);
    }
    __syncthreads();

    // ---- P3: htilde0 = tanh([rh0|x] @ Wc0 + bc0); h0 update ----
    f32x4 ac = {bc0c, bc0c, bc0c, bc0c};
#pragma unroll
    for (int kt = 0; kt < 8; ++kt) {
      bf16x8 a = *(const bf16x8*)(A0r + (kt << 9) + (lane << 3));
      ac = MFMA(a, pc[kt], ac);
    }
#pragma unroll
    for (int kt = 8; kt < 10; ++kt) {
      bf16x8 a = *(const bf16x8*)(xb + ((kt - 8) << 9) + (lane << 3));
      ac = MFMA(a, pc[kt], ac);
    }
#pragma unroll
    for (int i = 0; i < 4; ++i) {
      float ht = tanh_(ac[i]);
      float hn = h0[i] + z0[i] * (ht - h0[i]);
      h0[i] = hn;
      unsigned short hb = f2bf(hn);
      A0[dlo + i * 8]  = hb;   // next step's combined0 h-part
      A1[dhi + i * 8]  = hb;   // combined1 h0-part (k=256+colz)
      A1r[dhi + i * 8] = hb;   // reset1 h0-part
    }
    __syncthreads();

    // ---- P4: gates1 = [h1|h0] @ Wz1[:,:512] + bz1 ----
    f32x4 az1 = {bz1z, bz1z, bz1z, bz1z};
    f32x4 ar1 = {bz1r, bz1r, bz1r, bz1r};
#pragma unroll
    for (int kt = 0; kt < 16; ++kt) {
      bf16x8 a = *(const bf16x8*)(A1 + (kt << 9) + (lane << 3));
      az1 = MFMA(a, qz[kt], az1);
      ar1 = MFMA(a, qr[kt], ar1);
    }
    float z1[4];
#pragma unroll
    for (int i = 0; i < 4; ++i) {
      z1[i] = sigm(az1[i]);
      A1r[dlo + i * 8] = f2bf(sigm(ar1[i]) * h1[i]);
    }
    __syncthreads();

    // ---- P5: htilde1; h1 update; stage x[t+1] ----
    if (havex) {
      unsigned short* xb1 = xbuf + (((t + 1) & 1) << 10);
      xb1[xdst] = f2bf(sanit(xn));
    }
    f32x4 ac1 = {bc1c, bc1c, bc1c, bc1c};
#pragma unroll
    for (int kt = 0; kt < 16; ++kt) {
      bf16x8 a = *(const bf16x8*)(A1r + (kt << 9) + (lane << 3));
      ac1 = MFMA(a, qc[kt], ac1);
    }
#pragma unroll
    for (int i = 0; i < 4; ++i) {
      float ht = tanh_(ac1[i]);
      h1[i] = h1[i] + z1[i] * (ht - h1[i]);
      A1[dlo + i * 8] = f2bf(h1[i]);   // next step's combined1 h1-part
    }
    __syncthreads();
  }

  // ---- Epilogue: LayerNorm(h1) per row (fp32 state via LDS) ----
  float* h1buf = (float*)lds;  // frag buffers dead; 16x256 fp32 = 16 KB
#pragma unroll
  for (int i = 0; i < 4; ++i) h1buf[((quad << 2) + i) * 256 + colz] = h1[i];
  __syncthreads();

  float v[4], s = 0.f, sq = 0.f;
#pragma unroll
  for (int j = 0; j < 4; ++j) {
    v[j] = h1buf[wave * 256 + lane + (j << 6)];
    s += v[j];
    sq += v[j] * v[j];
  }
#pragma unroll
  for (int off = 32; off > 0; off >>= 1) {
    s  += __shfl_xor(s, off);
    sq += __shfl_xor(sq, off);
  }
  float mean = s * (1.f / 256.f);
  float var  = sq * (1.f / 256.f) - mean * mean;   // population var (jnp.var)
  float rstd = rsqrtf(var + 1e-5f);
  float* op = out + (size_t)(row0 + wave) * 256;
#pragma unroll
  for (int j = 0; j < 4; ++j) {
    int c = lane + (j << 6);
    op[c] = (v[j] - mean) * rstd * gamma[c] + beta[c];
  }
}

extern "C" void kernel_launch(void* const* d_in, const int* in_sizes, int n_in,
                              void* d_out, int out_size, void* d_ws, size_t ws_size,
                              hipStream_t stream) {
  const float* x     = (const float*)d_in[0];
  const float* Wz0   = (const float*)d_in[1];
  const float* bz0   = (const float*)d_in[2];
  const float* Wc0   = (const float*)d_in[3];
  const float* bc0   = (const float*)d_in[4];
  const float* Wz1   = (const float*)d_in[5];
  const float* bz1   = (const float*)d_in[6];
  const float* Wc1   = (const float*)d_in[7];
  const float* bc1   = (const float*)d_in[8];
  const float* gamma = (const float*)d_in[9];
  const float* beta  = (const float*)d_in[10];
  unsigned short* ws = (unsigned short*)d_ws;
  float* out = (float*)d_out;

  hipLaunchKernelGGL(prep_weights, dim3(2496), dim3(256), 0, stream, Wz0, Wc0, Wz1, Wc1, ws);
  hipLaunchKernelGGL(gru_main, dim3(16), dim3(1024), 0, stream,
                     x, bz0, bc0, bz1, bc1, gamma, beta, ws, out);
}

// Round 15
// 3136.397 us; speedup vs baseline: 5.2985x; 5.2985x over previous
//
#include <hip/hip_runtime.h>

// TimeframeEncoder R15: R13 with HALVED SYNC COUNT at constant ring bytes --
// the discriminating experiment between the two surviving channel theories:
// (a) ~9us fixed cost per cross-CU sync (256 syncs ~= 2.3ms) vs (b) ~140GB/s
// coherent-drain byte cap (270MB/3.1ms). CH 8->16, NCH 64->32, DEPTH 4->2
// (ring footprint byte-identical to R11/R13's proven 17MB). Plus: B's partial
// stores re-laid out from 12x8B to 6x16B wave-coalesced (C reads mirrored).
// R14 closed the register question: per-SIMD pool = 512 regs/lane (128KB) ->
// 512KB/CU; 1.22MB weights can NEVER be single-CU-resident; 3-stage split is
// structural. 16 groups x 3 blocks (256 thr = 4 waves, 512 regs/wave).

#define SEQL 512
#define CH 16
#define NCH 32
#define DEPTH 2

#define RB0  1310720u                   // rings base (weights end 1,277,952)
#define GSTR 1048576u                   // per group: 2x128KB h0 + 2x384KB partials
#define CTRB (RB0 + 16u * GSTR)         // counters: 16 groups x 64 B

typedef __bf16 bf16x8 __attribute__((ext_vector_type(8)));
typedef float f32x4 __attribute__((ext_vector_type(4)));
typedef unsigned long long u64;

__device__ __forceinline__ unsigned short f2bf(float f) {
  unsigned int u = __builtin_bit_cast(unsigned int, f);
  u += 0x7fffu + ((u >> 16) & 1u);
  return (unsigned short)(u >> 16);
}
__device__ __forceinline__ float bf2f(unsigned short u) {
  unsigned int v = ((unsigned int)u) << 16;
  return __builtin_bit_cast(float, v);
}
__device__ __forceinline__ float sigm(float x) { return 1.0f / (1.0f + __expf(-x)); }
__device__ __forceinline__ float tanh_(float x) { return 1.0f - 2.0f / (__expf(2.0f * x) + 1.0f); }
__device__ __forceinline__ float sanit(float v) {
  if (!(v == v)) return 0.f;
  if (isinf(v)) return v > 0.f ? 10.f : -10.f;
  return v;
}

// Weight prep (layout verified R1-R14): bf16 B-fragments, tile = 512 ushort,
// lane L holds B[k=(L>>4)*8+j][n=L&15]. Wz0p tiles [0,320) (nt<32,kt<10);
// Wc0p base 320 (nt<16,kt<10); Wz1p base 480 (nt<32,kt<16); Wc1p base 992.
__global__ __launch_bounds__(256) void prep_weights(
    const float* __restrict__ Wz0, const float* __restrict__ Wc0,
    const float* __restrict__ Wz1, const float* __restrict__ Wc1,
    unsigned short* __restrict__ ws) {
  int idx = blockIdx.x * 256 + threadIdx.x;  // 638976 threads
  const float* W;
  int stride, KT, base;
  if (idx < 163840)      { W = Wz0; stride = 768; KT = 10; base = 0; }
  else if (idx < 245760) { W = Wc0; stride = 256; KT = 10; base = 163840; idx -= 163840; }
  else if (idx < 507904) { W = Wz1; stride = 768; KT = 16; base = 245760; idx -= 245760; }
  else                   { W = Wc1; stride = 256; KT = 16; base = 507904; idx -= 507904; }
  int tile = idx >> 9;
  int t = idx & 511;
  int nt = tile / KT;
  int kt = tile - nt * KT;
  int n15 = t & 15;
  int klocal = t >> 4;
  int k = (kt << 5) + klocal;
  int n = (nt << 4) + n15;
  int lane = ((klocal >> 3) << 4) | n15;
  int j = klocal & 7;
  ws[base + (tile << 9) + (lane << 3) + j] = f2bf(W[k * stride + n]);
}

// counter poll (uncached relaxed atomic; proven correct/visible R8-R13)
__device__ __forceinline__ void waitge(int* p, int v, int tid) {
  __syncthreads();
  if (tid == 0) {
    long it = 0;
    while (__hip_atomic_load(p, __ATOMIC_RELAXED, __HIP_MEMORY_SCOPE_AGENT) < v) {
      __builtin_amdgcn_s_sleep(1);
      if (++it > (1L << 24)) break;  // valve against true deadlock
    }
  }
  __syncthreads();
}
// consumer acquire: after counter observed, ONE device fence (inv) per block
__device__ __forceinline__ void waitge_acq(int* p, int v, int tid) {
  waitge(p, v, tid);
  if (tid == 0) __threadfence();
  __syncthreads();
}
// producer release: all waves drain stores, barrier, ONE device fence (wbl2)
// from tid0, then uncached counter store.
__device__ __forceinline__ void publish_rel(int* p, int v, int tid) {
  asm volatile("s_waitcnt vmcnt(0)" ::: "memory");
  __syncthreads();
  if (tid == 0) {
    __threadfence();
    __hip_atomic_store(p, v, __ATOMIC_RELAXED, __HIP_MEMORY_SCOPE_AGENT);
  }
}
// ack publish (no data guarded -> no fence)
__device__ __forceinline__ void publish_ack(int* p, int v, int tid) {
  __syncthreads();
  if (tid == 0)
    __hip_atomic_store(p, v, __ATOMIC_RELAXED, __HIP_MEMORY_SCOPE_AGENT);
}

#define DLOC(c) ((((c) >> 5) << 9) + (((((c) >> 3) & 3) << 4) + (quad << 2)) * 8 + ((c) & 7))
#define MFMA(a, b, c) __builtin_amdgcn_mfma_f32_16x16x32_bf16((a), (b), (c), 0, 0, 0)

__global__ __launch_bounds__(256, 1) void gru_pipe(
    const float* __restrict__ x,
    const float* __restrict__ bz0, const float* __restrict__ bc0,
    const float* __restrict__ bz1, const float* __restrict__ bc1,
    const float* __restrict__ gamma, const float* __restrict__ beta,
    const unsigned short* __restrict__ wsw,
    unsigned short* __restrict__ gws,
    float* __restrict__ out) {
  __shared__ __align__(16) unsigned short lds[59392];  // 116 KB (stage A max)
  const int tid  = threadIdx.x;
  const int wave = tid >> 6;   // 0..3
  const int lane = tid & 63;
  const int l15  = lane & 15;
  const int quad = lane >> 4;
  const int stage = blockIdx.x >> 4;
  const int g     = blockIdx.x & 15;
  const int row0  = g << 4;

  const bf16x8* __restrict__ wsv = (const bf16x8*)wsw;
  unsigned short* ringh = gws + (RB0 >> 1) + (size_t)g * (GSTR >> 1);  // 2 x 65536 ushort
  unsigned short* ringp = ringh + 131072;                              // 2 x 196608 ushort
  int* ctr = (int*)((char*)gws + CTRB) + g * 16;  // [0]A_pub [1]B_pub [2]B_ack [3]C_ack

  if (stage == 0) {
    // ================= Stage A: layer0 =================
    unsigned short* h0f  = lds;            // 8 kt A-frag of h0
    unsigned short* rh0f = lds + 4096;
    unsigned short* xf   = lds + 8192;     // 2 bufs x 2 kt
    unsigned short* xw   = lds + 10240;    // x-part B tiles: 96 x 512 ushort
    for (int u = tid; u < 6144; u += 256) {
      int flat = u << 3, ti = flat >> 9, q = flat & 511, srct;
      if (ti < 64) srct = (ti >> 1) * 10 + 8 + (ti & 1);
      else         srct = 320 + ((ti - 64) >> 1) * 10 + 8 + (ti & 1);
      *(uint4*)(xw + flat) = *(const uint4*)(wsw + srct * 512 + q);
    }
    for (int i = tid; i < 4096; i += 256) h0f[i] = 0;

    bf16x8 pz[4][8], pr[4][8], pc[4][8];   // 96 tiles pinned (unified VGPR/AGPR)
#pragma unroll
    for (int j = 0; j < 4; ++j) {
      const int zt = 4 * wave + j;
#pragma unroll
      for (int k = 0; k < 8; ++k) {
        pz[j][k] = wsv[(zt * 10 + k) * 64 + lane];
        pr[j][k] = wsv[((16 + zt) * 10 + k) * 64 + lane];
        pc[j][k] = wsv[(320 + zt * 10 + k) * 64 + lane];
      }
    }
#pragma unroll
    for (int j = 0; j < 4; ++j)
#pragma unroll
      for (int k = 0; k < 8; ++k)
        asm volatile("" : "+v"(pz[j][k]), "+v"(pr[j][k]), "+v"(pc[j][k]));

    float bzz[4], bzr[4], bcc[4];
    int dloc[4];
#pragma unroll
    for (int j = 0; j < 4; ++j) {
      const int col = 64 * wave + 16 * j + l15;
      bzz[j] = bz0[col]; bzr[j] = bz0[256 + col]; bcc[j] = bc0[col];
      dloc[j] = DLOC(col);
    }
    f32x4 h0s[4] = {{0,0,0,0},{0,0,0,0},{0,0,0,0},{0,0,0,0}};

    const int xrow = tid >> 4, c4 = (tid & 15) << 2;
    const float* xp = x + (size_t)(row0 + xrow) * (SEQL * 64) + c4;
    const int xbase = ((c4 >> 5) << 9) + ((((c4 >> 3) & 3) << 4) + xrow) * 8 + (c4 & 7);
    {
      float4 xv = *(const float4*)xp;
      xf[xbase] = f2bf(sanit(xv.x)); xf[xbase + 1] = f2bf(sanit(xv.y));
      xf[xbase + 2] = f2bf(sanit(xv.z)); xf[xbase + 3] = f2bf(sanit(xv.w));
    }
    __syncthreads();

    for (int ch = 0; ch < NCH; ++ch) {
      if (ch >= DEPTH) waitge(ctr + 2, ch - (DEPTH - 1), tid);   // B freed this slot
      unsigned short* slot = ringh + (ch & (DEPTH - 1)) * (CH * 4096);
      for (int s = 0; s < CH; ++s) {
        const int t = ch * CH + s;
        if (s > 0) {  // full 4096-ushort frame of prev step's h0 (cached stores)
          unsigned short* dst = slot + (s - 1) * 4096;
          *(uint4*)(dst + tid * 8)        = *(const uint4*)(h0f + tid * 8);
          *(uint4*)(dst + 2048 + tid * 8) = *(const uint4*)(h0f + 2048 + tid * 8);
        }
        const unsigned short* xb = xf + ((t & 1) << 10);
        const bool havex = (t + 1 < SEQL);
        float4 xn;
        if (havex) xn = *(const float4*)(xp + (t + 1) * 64);

        f32x4 za[4], ra[4];
#pragma unroll
        for (int j = 0; j < 4; ++j) { za[j] = {bzz[j],bzz[j],bzz[j],bzz[j]}; ra[j] = {bzr[j],bzr[j],bzr[j],bzr[j]}; }
#pragma unroll
        for (int k = 0; k < 8; ++k) {
          bf16x8 a = *(const bf16x8*)(h0f + (k << 9) + (lane << 3));
#pragma unroll
          for (int j = 0; j < 4; ++j) { za[j] = MFMA(a, pz[j][k], za[j]); ra[j] = MFMA(a, pr[j][k], ra[j]); }
        }
#pragma unroll
        for (int k = 0; k < 2; ++k) {
          bf16x8 a = *(const bf16x8*)(xb + (k << 9) + (lane << 3));
#pragma unroll
          for (int j = 0; j < 4; ++j) {
            bf16x8 bz_ = *(const bf16x8*)(xw + ((((4 * wave + j) << 1) | k) << 9) + (lane << 3));
            bf16x8 br_ = *(const bf16x8*)(xw + ((((16 + 4 * wave + j) << 1) | k) << 9) + (lane << 3));
            za[j] = MFMA(a, bz_, za[j]); ra[j] = MFMA(a, br_, ra[j]);
          }
        }
        float zg[4][4];
#pragma unroll
        for (int j = 0; j < 4; ++j)
#pragma unroll
          for (int i = 0; i < 4; ++i) {
            zg[j][i] = sigm(za[j][i]);
            rh0f[dloc[j] + i * 8] = f2bf(sigm(ra[j][i]) * h0s[j][i]);
          }
        __syncthreads();

        f32x4 ca[4];
#pragma unroll
        for (int j = 0; j < 4; ++j) ca[j] = {bcc[j],bcc[j],bcc[j],bcc[j]};
#pragma unroll
        for (int k = 0; k < 8; ++k) {
          bf16x8 a = *(const bf16x8*)(rh0f + (k << 9) + (lane << 3));
#pragma unroll
          for (int j = 0; j < 4; ++j) ca[j] = MFMA(a, pc[j][k], ca[j]);
        }
#pragma unroll
        for (int k = 0; k < 2; ++k) {
          bf16x8 a = *(const bf16x8*)(xb + (k << 9) + (lane << 3));
#pragma unroll
          for (int j = 0; j < 4; ++j) {
            bf16x8 bc_ = *(const bf16x8*)(xw + 32768 + ((((4 * wave + j) << 1) | k) << 9) + (lane << 3));
            ca[j] = MFMA(a, bc_, ca[j]);
          }
        }
#pragma unroll
        for (int j = 0; j < 4; ++j)
#pragma unroll
          for (int i = 0; i < 4; ++i) {
            float ht = tanh_(ca[j][i]);
            float hn = h0s[j][i] + zg[j][i] * (ht - h0s[j][i]);
            h0s[j][i] = hn;
            h0f[dloc[j] + i * 8] = f2bf(hn);
          }
        if (havex) {
          unsigned short* xb1 = xf + (((t + 1) & 1) << 10);
          xb1[xbase] = f2bf(sanit(xn.x)); xb1[xbase + 1] = f2bf(sanit(xn.y));
          xb1[xbase + 2] = f2bf(sanit(xn.z)); xb1[xbase + 3] = f2bf(sanit(xn.w));
        }
        __syncthreads();
      }
      {  // final frame of the chunk
        unsigned short* dst = slot + (CH - 1) * 4096;
        *(uint4*)(dst + tid * 8)        = *(const uint4*)(h0f + tid * 8);
        *(uint4*)(dst + 2048 + tid * 8) = *(const uint4*)(h0f + 2048 + tid * 8);
      }
      publish_rel(ctr + 0, ch + 1, tid);
    }
  } else if (stage == 1) {
    // ============ Stage B: layer1 h0-contribution (pure GEMM) ============
    bf16x8 p1[4][8], p2[4][8], p3[4][8];  // Wz1-z, Wz1-r, Wc1 h0-halves (kt 8..15)
#pragma unroll
    for (int j = 0; j < 4; ++j) {
      const int nt = 4 * wave + j;
#pragma unroll
      for (int k = 0; k < 8; ++k) {
        p1[j][k] = wsv[(480 + nt * 16 + 8 + k) * 64 + lane];
        p2[j][k] = wsv[(480 + (16 + nt) * 16 + 8 + k) * 64 + lane];
        p3[j][k] = wsv[(992 + nt * 16 + 8 + k) * 64 + lane];
      }
    }
#pragma unroll
    for (int j = 0; j < 4; ++j)
#pragma unroll
      for (int k = 0; k < 8; ++k)
        asm volatile("" : "+v"(p1[j][k]), "+v"(p2[j][k]), "+v"(p3[j][k]));
    float b1[4], b2[4], b3[4];
#pragma unroll
    for (int j = 0; j < 4; ++j) {
      const int col = 64 * wave + 16 * j + l15;
      b1[j] = bz1[col]; b2[j] = bz1[256 + col]; b3[j] = bc1[col];
    }
    for (int ch = 0; ch < NCH; ++ch) {
      waitge_acq(ctr + 0, ch + 1, tid);                   // A published (inv)
      if (ch >= DEPTH) waitge(ctr + 3, ch - (DEPTH - 1), tid);  // C freed p-slot
      const unsigned short* hslot = ringh + (ch & (DEPTH - 1)) * (CH * 4096);
      unsigned short* pslot = ringp + (ch & (DEPTH - 1)) * (CH * 12288);
      for (int s = 0; s < CH; ++s) {
        const unsigned short* hf = hslot + s * 4096;
        f32x4 za[4] = {{0,0,0,0},{0,0,0,0},{0,0,0,0},{0,0,0,0}};
        f32x4 ra[4] = {{0,0,0,0},{0,0,0,0},{0,0,0,0},{0,0,0,0}};
        f32x4 ca[4] = {{0,0,0,0},{0,0,0,0},{0,0,0,0},{0,0,0,0}};
#pragma unroll
        for (int k = 0; k < 8; ++k) {
          bf16x8 a = *(const bf16x8*)(hf + (k << 9) + (lane << 3));   // cached, pipelined
#pragma unroll
          for (int j = 0; j < 4; ++j) {
            za[j] = MFMA(a, p1[j][k], za[j]);
            ra[j] = MFMA(a, p2[j][k], ra[j]);
            ca[j] = MFMA(a, p3[j][k], ca[j]);
          }
        }
        // partial pack: 12 u64 per thread -> 6 wave-coalesced uint4 stores
        u64 pv[12];
#pragma unroll
        for (int j = 0; j < 4; ++j) {
          ushort4 vz, vr, vc;
          vz.x = f2bf(za[j][0] + b1[j]); vz.y = f2bf(za[j][1] + b1[j]);
          vz.z = f2bf(za[j][2] + b1[j]); vz.w = f2bf(za[j][3] + b1[j]);
          vr.x = f2bf(ra[j][0] + b2[j]); vr.y = f2bf(ra[j][1] + b2[j]);
          vr.z = f2bf(ra[j][2] + b2[j]); vr.w = f2bf(ra[j][3] + b2[j]);
          vc.x = f2bf(ca[j][0] + b3[j]); vc.y = f2bf(ca[j][1] + b3[j]);
          vc.z = f2bf(ca[j][2] + b3[j]); vc.w = f2bf(ca[j][3] + b3[j]);
          pv[j]     = __builtin_bit_cast(u64, vz);
          pv[4 + j] = __builtin_bit_cast(u64, vr);
          pv[8 + j] = __builtin_bit_cast(u64, vc);
        }
        uint4* pf4 = (uint4*)(pslot + s * 12288);
        const uint4* src = (const uint4*)pv;
#pragma unroll
        for (int q = 0; q < 6; ++q)
          pf4[(wave * 6 + q) * 64 + lane] = src[q];
      }
      publish_rel(ctr + 1, ch + 1, tid);
      if (tid == 0)
        __hip_atomic_store(ctr + 2, ch + 1, __ATOMIC_RELAXED, __HIP_MEMORY_SCOPE_AGENT);
    }
  } else {
    // ============ Stage C: layer1 recurrence + LN output ============
    unsigned short* h1f  = lds;
    unsigned short* rh1f = lds + 4096;
    bf16x8 q1[4][8], q2[4][8], q3[4][8];  // h1-halves (kt 0..7)
#pragma unroll
    for (int j = 0; j < 4; ++j) {
      const int nt = 4 * wave + j;
#pragma unroll
      for (int k = 0; k < 8; ++k) {
        q1[j][k] = wsv[(480 + nt * 16 + k) * 64 + lane];
        q2[j][k] = wsv[(480 + (16 + nt) * 16 + k) * 64 + lane];
        q3[j][k] = wsv[(992 + nt * 16 + k) * 64 + lane];
      }
    }
#pragma unroll
    for (int j = 0; j < 4; ++j)
#pragma unroll
      for (int k = 0; k < 8; ++k)
        asm volatile("" : "+v"(q1[j][k]), "+v"(q2[j][k]), "+v"(q3[j][k]));
    for (int i = tid; i < 4096; i += 256) h1f[i] = 0;
    int dloc[4];
#pragma unroll
    for (int j = 0; j < 4; ++j) dloc[j] = DLOC(64 * wave + 16 * j + l15);
    f32x4 h1s[4] = {{0,0,0,0},{0,0,0,0},{0,0,0,0},{0,0,0,0}};
    __syncthreads();

    for (int ch = 0; ch < NCH; ++ch) {
      waitge_acq(ctr + 1, ch + 1, tid);                   // B published (inv)
      const unsigned short* pslot = ringp + (ch & (DEPTH - 1)) * (CH * 12288);
      for (int s = 0; s < CH; ++s) {
        // mirrored 6x16B coalesced reads -> 12 u64 per thread
        uint4 pq[6];
        const uint4* pf4 = (const uint4*)(pslot + s * 12288);
#pragma unroll
        for (int q = 0; q < 6; ++q) pq[q] = pf4[(wave * 6 + q) * 64 + lane];
        const u64* pv = (const u64*)pq;  // [0..3]=z, [4..7]=r, [8..11]=c

        f32x4 za[4] = {{0,0,0,0},{0,0,0,0},{0,0,0,0},{0,0,0,0}};
        f32x4 ra[4] = {{0,0,0,0},{0,0,0,0},{0,0,0,0},{0,0,0,0}};
#pragma unroll
        for (int k = 0; k < 8; ++k) {
          bf16x8 a = *(const bf16x8*)(h1f + (k << 9) + (lane << 3));
#pragma unroll
          for (int j = 0; j < 4; ++j) { za[j] = MFMA(a, q1[j][k], za[j]); ra[j] = MFMA(a, q2[j][k], ra[j]); }
        }
        float zg[4][4];
#pragma unroll
        for (int j = 0; j < 4; ++j) {
          ushort4 uz = __builtin_bit_cast(ushort4, pv[j]);
          ushort4 ur = __builtin_bit_cast(ushort4, pv[4 + j]);
          const unsigned short* pzs = (const unsigned short*)&uz;
          const unsigned short* prs = (const unsigned short*)&ur;
#pragma unroll
          for (int i = 0; i < 4; ++i) {
            zg[j][i] = sigm(za[j][i] + bf2f(pzs[i]));
            float r = sigm(ra[j][i] + bf2f(prs[i]));
            rh1f[dloc[j] + i * 8] = f2bf(r * h1s[j][i]);
          }
        }
        __syncthreads();

        f32x4 ca[4] = {{0,0,0,0},{0,0,0,0},{0,0,0,0},{0,0,0,0}};
#pragma unroll
        for (int k = 0; k < 8; ++k) {
          bf16x8 a = *(const bf16x8*)(rh1f + (k << 9) + (lane << 3));
#pragma unroll
          for (int j = 0; j < 4; ++j) ca[j] = MFMA(a, q3[j][k], ca[j]);
        }
#pragma unroll
        for (int j = 0; j < 4; ++j) {
          ushort4 uc = __builtin_bit_cast(ushort4, pv[8 + j]);
          const unsigned short* pcs = (const unsigned short*)&uc;
#pragma unroll
          for (int i = 0; i < 4; ++i) {
            float ht = tanh_(ca[j][i] + bf2f(pcs[i]));
            float hn = h1s[j][i] + zg[j][i] * (ht - h1s[j][i]);
            h1s[j][i] = hn;
            h1f[dloc[j] + i * 8] = f2bf(hn);
          }
        }
        __syncthreads();
      }
      publish_ack(ctr + 3, ch + 1, tid);
    }

    // LayerNorm from fp32 h1 state via LDS staging
    float* h1buf = (float*)lds;   // 16 x 256 fp32 = 16 KB
#pragma unroll
    for (int j = 0; j < 4; ++j)
#pragma unroll
      for (int i = 0; i < 4; ++i)
        h1buf[(quad * 4 + i) * 256 + 64 * wave + 16 * j + l15] = h1s[j][i];
    __syncthreads();

    const int r = tid >> 4, cl = tid & 15;
    float v[16], s = 0.f, sq = 0.f;
#pragma unroll
    for (int jj = 0; jj < 16; ++jj) {
      v[jj] = h1buf[r * 256 + cl + (jj << 4)];
      s += v[jj]; sq += v[jj] * v[jj];
    }
#pragma unroll
    for (int off = 8; off > 0; off >>= 1) {   // 16-lane group reduce
      s  += __shfl_xor(s, off);
      sq += __shfl_xor(sq, off);
    }
    const float mean = s * (1.f / 256.f);
    const float var  = sq * (1.f / 256.f) - mean * mean;
    const float rstd = rsqrtf(var + 1e-5f);
    float* op = out + (size_t)(row0 + r) * 256;
#pragma unroll
    for (int jj = 0; jj < 16; ++jj) {
      const int c = cl + (jj << 4);
      op[c] = (v[jj] - mean) * rstd * gamma[c] + beta[c];
    }
  }
}

extern "C" void kernel_launch(void* const* d_in, const int* in_sizes, int n_in,
                              void* d_out, int out_size, void* d_ws, size_t ws_size,
                              hipStream_t stream) {
  const float* x     = (const float*)d_in[0];
  const float* Wz0   = (const float*)d_in[1];
  const float* bz0   = (const float*)d_in[2];
  const float* Wc0   = (const float*)d_in[3];
  const float* bc0   = (const float*)d_in[4];
  const float* Wz1   = (const float*)d_in[5];
  const float* bz1   = (const float*)d_in[6];
  const float* Wc1   = (const float*)d_in[7];
  const float* bc1   = (const float*)d_in[8];
  const float* gamma = (const float*)d_in[9];
  const float* beta  = (const float*)d_in[10];
  unsigned short* ws = (unsigned short*)d_ws;
  float* out = (float*)d_out;

  hipMemsetAsync((char*)d_ws + CTRB, 0, 1024, stream);
  hipLaunchKernelGGL(prep_weights, dim3(2496), dim3(256), 0, stream, Wz0, Wc0, Wz1, Wc1, ws);
  hipLaunchKernelGGL(gru_pipe, dim3(48), dim3(256), 0, stream,
                     x, bz0, bc0, bz1, bc1, gamma, beta, ws, ws, out);
}